// Round 5
// baseline (290.254 us; speedup 1.0000x reference)
//
#include <hip/hip_runtime.h>
#include <hip/hip_bf16.h>

#define B_   2
#define SQ_  2048
#define DM_  1024
#define NH_  16
#define DH_  64

typedef __attribute__((ext_vector_type(8))) short          bf16x8;
typedef __attribute__((ext_vector_type(8))) unsigned short u16x8;
typedef __attribute__((ext_vector_type(4))) float          f32x4;

__device__ __forceinline__ unsigned short f2bf(float f) {
    union { __hip_bfloat16 h; unsigned short u; } c;
    c.h = __float2bfloat16(f);   // RNE
    return c.u;
}
__device__ __forceinline__ float gsum16(float v) {
    v += __shfl_xor(v, 1);
    v += __shfl_xor(v, 2);
    v += __shfl_xor(v, 4);
    v += __shfl_xor(v, 8);
    return v;
}

// All four weight transposes in one launch. dst[c][r] = bf16(src[r][c]).
// bid<768: W_Q/W_K/W_V (each 16 mats of 1024x64, 256 blocks each).
// bid>=768: W_O (1024x1024, 256 blocks).
__global__ __launch_bounds__(256) void transpose_all(
    const float* __restrict__ W_Q, const float* __restrict__ W_K,
    const float* __restrict__ W_V, const float* __restrict__ W_O,
    unsigned short* __restrict__ WTq, unsigned short* __restrict__ WTkv,
    unsigned short* __restrict__ WTo)
{
    __shared__ float t[64][65];
    const int bid = blockIdx.x;
    const float* src; unsigned short* dst; int R, C, r0, c0;
    if (bid < 768) {
        const int which = bid >> 8, rem = bid & 255;
        const int rblk = rem & 15, zz = rem >> 4;
        src = (which == 0) ? W_Q : (which == 1) ? W_K : W_V;
        dst = (which == 0) ? WTq : (which == 1) ? WTkv : (WTkv + (1u << 20));
        src += (size_t)65536 * zz;
        dst += (size_t)65536 * zz;
        R = 1024; C = 64; r0 = rblk * 64; c0 = 0;
    } else {
        const int rem = bid - 768;
        src = W_O; dst = WTo; R = 1024; C = 1024;
        r0 = (rem & 15) * 64; c0 = (rem >> 4) * 64;
    }
    const int lr = threadIdx.x >> 6, lc = threadIdx.x & 63;
#pragma unroll
    for (int i = 0; i < 16; ++i)
        t[lr + i * 4][lc] = src[(size_t)(r0 + lr + i * 4) * C + c0 + lc];
    __syncthreads();
#pragma unroll
    for (int i = 0; i < 16; ++i)
        dst[(size_t)(c0 + lr + i * 4) * R + r0 + lc] = f2bf(t[lc][lr + i * 4]);
}

// C[4096 x N] = A[4096 x 1024] * W(+bias).  WT bf16 [c][k], row stride 1024.
// TM=128, BK=64, 256 threads.
// TN=128: waves 2x2 (64x64 each).  TN=64: waves 4x1 (32x64 each).
// MODE 0: Q  -> per-head LN, bf16 out (Cb)
// MODE 1: KV -> N=2048; cols<1024: K (LN, f32 Cf + bf16 Cb); cols>=1024: V
//               (f32 Cf2 row-major + bf16 CbT transposed [b][h][d][s])
// MODE 2: O  -> f32 out (Cf)
template <int TN, int A_BF16, int MODE>
__device__ __forceinline__ void gemm_body(
    unsigned short (*__restrict__ As)[72], unsigned short (*__restrict__ Bs)[72],
    int bx, int by, const void* __restrict__ Asrc, const unsigned short* __restrict__ WT,
    const float* __restrict__ biasK, const float* __restrict__ biasV,
    const float* __restrict__ lnw, const float* __restrict__ lnb,
    float* __restrict__ Cf, float* __restrict__ Cf2,
    unsigned short* __restrict__ Cb, unsigned short* __restrict__ CbT, int tid)
{
    constexpr int MI = (TN == 128) ? 4 : 2;
    constexpr int BP = TN / 64;

    const int m0 = by * 128;
    const int c0 = bx * TN;

    const int srow = tid >> 2;
    const int skc  = (tid & 3) * 16;

    float4 fa[2][4];
    u16x8  ba[2][2];
    u16x8  bb[BP][2];

    const int wid = tid >> 6, lane = tid & 63;
    const int wm = (TN == 128) ? (wid >> 1) * 64 : wid * 32;
    const int wn = (TN == 128) ? (wid & 1) * 64 : 0;
    const int l15 = lane & 15, qd = lane >> 4;

    const f32x4 zero4 = {0.f, 0.f, 0.f, 0.f};
    f32x4 acc[MI][4];
#pragma unroll
    for (int mi = 0; mi < MI; ++mi)
#pragma unroll
        for (int ni = 0; ni < 4; ++ni) acc[mi][ni] = zero4;

#define LOAD_A(kb)                                                              \
    {                                                                           \
        const size_t kof = (size_t)(kb) * 64 + skc;                             \
        if constexpr (!A_BF16) {                                                \
            const float* A = (const float*)Asrc;                                \
            for (int p = 0; p < 2; ++p) {                                       \
                const float* s = A + (size_t)(m0 + srow + p * 64) * 1024 + kof; \
                fa[p][0] = *(const float4*)(s + 0);                             \
                fa[p][1] = *(const float4*)(s + 4);                             \
                fa[p][2] = *(const float4*)(s + 8);                             \
                fa[p][3] = *(const float4*)(s + 12);                            \
            }                                                                   \
        } else {                                                                \
            const unsigned short* A = (const unsigned short*)Asrc;              \
            for (int p = 0; p < 2; ++p) {                                       \
                const unsigned short* s =                                       \
                    A + (size_t)(m0 + srow + p * 64) * 1024 + kof;              \
                ba[p][0] = *(const u16x8*)(s + 0);                              \
                ba[p][1] = *(const u16x8*)(s + 8);                              \
            }                                                                   \
        }                                                                       \
        for (int p = 0; p < BP; ++p) {                                          \
            const unsigned short* s =                                           \
                WT + (size_t)(c0 + srow + p * 64) * 1024 + kof;                 \
            bb[p][0] = *(const u16x8*)(s + 0);                                  \
            bb[p][1] = *(const u16x8*)(s + 8);                                  \
        }                                                                       \
    }

    LOAD_A(0)
    for (int kb = 0; kb < 16; ++kb) {
        __syncthreads();
#pragma unroll
        for (int p = 0; p < 2; ++p) {
            if constexpr (!A_BF16) {
                u16x8 lo, hi;
                lo[0] = f2bf(fa[p][0].x); lo[1] = f2bf(fa[p][0].y);
                lo[2] = f2bf(fa[p][0].z); lo[3] = f2bf(fa[p][0].w);
                lo[4] = f2bf(fa[p][1].x); lo[5] = f2bf(fa[p][1].y);
                lo[6] = f2bf(fa[p][1].z); lo[7] = f2bf(fa[p][1].w);
                hi[0] = f2bf(fa[p][2].x); hi[1] = f2bf(fa[p][2].y);
                hi[2] = f2bf(fa[p][2].z); hi[3] = f2bf(fa[p][2].w);
                hi[4] = f2bf(fa[p][3].x); hi[5] = f2bf(fa[p][3].y);
                hi[6] = f2bf(fa[p][3].z); hi[7] = f2bf(fa[p][3].w);
                *(u16x8*)&As[srow + p * 64][skc + 0] = lo;
                *(u16x8*)&As[srow + p * 64][skc + 8] = hi;
            } else {
                *(u16x8*)&As[srow + p * 64][skc + 0] = ba[p][0];
                *(u16x8*)&As[srow + p * 64][skc + 8] = ba[p][1];
            }
        }
#pragma unroll
        for (int p = 0; p < BP; ++p) {
            *(u16x8*)&Bs[srow + p * 64][skc + 0] = bb[p][0];
            *(u16x8*)&Bs[srow + p * 64][skc + 8] = bb[p][1];
        }
        __syncthreads();
        if (kb < 15) LOAD_A(kb + 1)
#pragma unroll
        for (int ks = 0; ks < 2; ++ks) {
            bf16x8 af[MI], bfr[4];
#pragma unroll
            for (int mi = 0; mi < MI; ++mi)
                af[mi] = *(const bf16x8*)&As[wm + mi * 16 + l15][ks * 32 + qd * 8];
#pragma unroll
            for (int ni = 0; ni < 4; ++ni)
                bfr[ni] = *(const bf16x8*)&Bs[wn + ni * 16 + l15][ks * 32 + qd * 8];
#pragma unroll
            for (int mi = 0; mi < MI; ++mi)
#pragma unroll
                for (int ni = 0; ni < 4; ++ni)
                    acc[mi][ni] = __builtin_amdgcn_mfma_f32_16x16x32_bf16(
                        af[mi], bfr[ni], acc[mi][ni], 0, 0, 0);
        }
    }
#undef LOAD_A

    const float* bias = (MODE == 1 && c0 >= 1024) ? biasV : biasK;
    float bv[4];
#pragma unroll
    for (int ni = 0; ni < 4; ++ni) bv[ni] = bias[(c0 + wn + ni * 16 + l15) & 1023];
#pragma unroll
    for (int mi = 0; mi < MI; ++mi)
#pragma unroll
        for (int ni = 0; ni < 4; ++ni)
#pragma unroll
            for (int r = 0; r < 4; ++r) acc[mi][ni][r] += bv[ni];

    if constexpr (MODE != 2) {
        const bool doLN = (MODE == 0) || (c0 < 1024);
        if (doLN) {   // per-head LN: wave's 64 cols = exactly one head
            float w4[4], lb4[4];
#pragma unroll
            for (int ni = 0; ni < 4; ++ni) {
                w4[ni]  = lnw[ni * 16 + l15];
                lb4[ni] = lnb[ni * 16 + l15];
            }
#pragma unroll
            for (int mi = 0; mi < MI; ++mi)
#pragma unroll
                for (int r = 0; r < 4; ++r) {
                    float s1 = acc[mi][0][r] + acc[mi][1][r] + acc[mi][2][r] + acc[mi][3][r];
                    const float mu = gsum16(s1) * (1.0f / 64.0f);
                    float s2 = acc[mi][0][r] * acc[mi][0][r] + acc[mi][1][r] * acc[mi][1][r]
                             + acc[mi][2][r] * acc[mi][2][r] + acc[mi][3][r] * acc[mi][3][r];
                    const float var = gsum16(s2) * (1.0f / 64.0f) - mu * mu;
                    const float rstd = rsqrtf(var + 1e-5f);
#pragma unroll
                    for (int ni = 0; ni < 4; ++ni)
                        acc[mi][ni][r] = (acc[mi][ni][r] - mu) * rstd * w4[ni] + lb4[ni];
                }
        }
    }

    if constexpr (MODE == 0) {
#pragma unroll
        for (int mi = 0; mi < MI; ++mi)
#pragma unroll
            for (int r = 0; r < 4; ++r) {
                const size_t grow = m0 + wm + mi * 16 + qd * 4 + r;
#pragma unroll
                for (int ni = 0; ni < 4; ++ni)
                    Cb[grow * 1024 + c0 + wn + ni * 16 + l15] = f2bf(acc[mi][ni][r]);
            }
    } else if constexpr (MODE == 2) {
#pragma unroll
        for (int mi = 0; mi < MI; ++mi)
#pragma unroll
            for (int r = 0; r < 4; ++r) {
                const size_t grow = m0 + wm + mi * 16 + qd * 4 + r;
#pragma unroll
                for (int ni = 0; ni < 4; ++ni)
                    Cf[grow * 1024 + c0 + wn + ni * 16 + l15] = acc[mi][ni][r];
            }
    } else {
        if (c0 < 1024) {   // K half
#pragma unroll
            for (int mi = 0; mi < MI; ++mi)
#pragma unroll
                for (int r = 0; r < 4; ++r) {
                    const size_t grow = m0 + wm + mi * 16 + qd * 4 + r;
#pragma unroll
                    for (int ni = 0; ni < 4; ++ni) {
                        const int gcol = c0 + wn + ni * 16 + l15;
                        Cf[grow * 1024 + gcol] = acc[mi][ni][r];
                        Cb[grow * 1024 + gcol] = f2bf(acc[mi][ni][r]);
                    }
                }
        } else {           // V half: row-major f32 + transposed bf16
#pragma unroll
            for (int mi = 0; mi < MI; ++mi) {
                const int growb = m0 + wm + mi * 16 + qd * 4;
                const int bb_ = growb >> 11, ss = growb & 2047;
#pragma unroll
                for (int ni = 0; ni < 4; ++ni) {
                    const int gv = c0 - 1024 + wn + ni * 16 + l15;
                    const int hh = gv >> 6, dd = gv & 63;
#pragma unroll
                    for (int r = 0; r < 4; ++r)
                        Cf2[(size_t)(growb + r) * 1024 + gv] = acc[mi][ni][r];
                    ushort4 w;
                    w.x = f2bf(acc[mi][ni][0]); w.y = f2bf(acc[mi][ni][1]);
                    w.z = f2bf(acc[mi][ni][2]); w.w = f2bf(acc[mi][ni][3]);
                    *(ushort4*)&CbT[(((size_t)bb_ * NH_ + hh) * DH_ + dd) * SQ_ + ss] = w;
                }
            }
        }
    }
}

// Q gemm (256 blocks) + KV gemm (512 blocks) fused in one 768-block launch.
__global__ __launch_bounds__(256) void qkv_fused(
    const float* __restrict__ x_q, const float* __restrict__ x_kv,
    const unsigned short* __restrict__ WTq, const unsigned short* __restrict__ WTkv,
    const float* __restrict__ b_Q, const float* __restrict__ b_K,
    const float* __restrict__ b_V,
    const float* __restrict__ ln1w, const float* __restrict__ ln1b,
    const float* __restrict__ ln2w, const float* __restrict__ ln2b,
    float* __restrict__ kout, float* __restrict__ vout,
    unsigned short* __restrict__ qz, unsigned short* __restrict__ kbf,
    unsigned short* __restrict__ vbfT)
{
    __shared__ __align__(16) unsigned short As[128][72];
    __shared__ __align__(16) unsigned short Bs[128][72];
    const int bid = blockIdx.x, tid = threadIdx.x;
    if (bid < 512) {
        gemm_body<128, 0, 1>(As, Bs, bid & 15, bid >> 4, x_kv, WTkv, b_K, b_V,
                             ln2w, ln2b, kout, vout, kbf, vbfT, tid);
    } else {
        const int b2 = bid - 512;
        gemm_body<128, 0, 0>(As, Bs, b2 & 7, b2 >> 3, x_q, WTq, b_Q, nullptr,
                             ln1w, ln1b, nullptr, nullptr, qz, nullptr, tid);
    }
}

__global__ __launch_bounds__(256) void o_gemm(
    const unsigned short* __restrict__ zbf, const unsigned short* __restrict__ WTo,
    const float* __restrict__ b_O, float* __restrict__ out)
{
    __shared__ __align__(16) unsigned short As[128][72];
    __shared__ __align__(16) unsigned short Bs[64][72];
    gemm_body<64, 1, 2>(As, Bs, blockIdx.x, blockIdx.y, zbf, WTo, b_O, nullptr,
                        nullptr, nullptr, out, nullptr, nullptr, nullptr, threadIdx.x);
}

// causal flash attention, S^T formulation; 128 q-rows/block, 4 waves x
// (2 groups x 16 q-cols); paired hi-lo q-blocks (uniform 34 kv-tiles/block).
__global__ __launch_bounds__(256) void attn_mfma(
    unsigned short* __restrict__ qz, const unsigned short* __restrict__ kbf,
    const unsigned short* __restrict__ vbfT)
{
    __shared__ __align__(16) unsigned short Ks[64][72];    // [kvrow][d]
    __shared__ __align__(16) unsigned short VsT[64][72];   // [d][kvrow]
    __shared__ __align__(16) unsigned short Ps[128][72];   // [qrow][kv] wave-private rows

    const int tid = threadIdx.x;
    const int h = blockIdx.y, b = blockIdx.z;
    const int wid = tid >> 6, lane = tid & 63;
    const int l15 = lane & 15, qd = lane >> 4;
    const int srow = tid >> 2, scol = (tid & 3) * 16;

    const size_t kbase = (size_t)b * SQ_ * DM_ + (size_t)h * DH_;
    const size_t vbase = ((size_t)b * NH_ + h) * DH_ * (size_t)SQ_;
    const f32x4 zero4 = {0.f, 0.f, 0.f, 0.f};

    for (int pass = 0; pass < 2; ++pass) {
        const int qt = pass ? blockIdx.x : 15 - blockIdx.x;   // 128-row q block

        // Q fragments, 2 groups (B-operand: n=l15 -> qcol, k -> d)
        bf16x8 qf[2][2];
#pragma unroll
        for (int g = 0; g < 2; ++g) {
            const unsigned short* qp = qz + kbase +
                (size_t)(qt * 128 + g * 64 + wid * 16 + l15) * DM_ + qd * 8;
            qf[g][0] = *(const bf16x8*)(qp);
            qf[g][1] = *(const bf16x8*)(qp + 32);
        }

        f32x4 z[2][4];
        float m_i[2], l_i[2];
#pragma unroll
        for (int g = 0; g < 2; ++g) {
            m_i[g] = -3.0e38f; l_i[g] = 0.f;
#pragma unroll
            for (int ni = 0; ni < 4; ++ni) z[g][ni] = zero4;
        }

        const int ktmax = 2 * qt + 1;
        u16x8 kr0, kr1, vr0, vr1;
        {
            const unsigned short* ks = kbf + kbase + (size_t)srow * DM_ + scol;
            kr0 = *(const u16x8*)(ks);
            kr1 = *(const u16x8*)(ks + 8);
            const unsigned short* vs = vbfT + vbase + (size_t)srow * SQ_ + scol;
            vr0 = *(const u16x8*)(vs);
            vr1 = *(const u16x8*)(vs + 8);
        }

        for (int kt = 0; kt <= ktmax; ++kt) {
            __syncthreads();   // prior tile's reads of Ks/VsT complete
            *(u16x8*)&Ks[srow][scol + 0]  = kr0;
            *(u16x8*)&Ks[srow][scol + 8]  = kr1;
            *(u16x8*)&VsT[srow][scol + 0] = vr0;
            *(u16x8*)&VsT[srow][scol + 8] = vr1;
            __syncthreads();
            if (kt < ktmax) {   // prefetch next tile (overlaps compute)
                const unsigned short* ks =
                    kbf + kbase + (size_t)((kt + 1) * 64 + srow) * DM_ + scol;
                kr0 = *(const u16x8*)(ks);
                kr1 = *(const u16x8*)(ks + 8);
                const unsigned short* vs =
                    vbfT + vbase + (size_t)srow * SQ_ + (kt + 1) * 64 + scol;
                vr0 = *(const u16x8*)(vs);
                vr1 = *(const u16x8*)(vs + 8);
            }

#pragma unroll
            for (int g = 0; g < 2; ++g) {
                const int diag = 2 * qt + g;
                if (kt > diag) continue;   // fully-masked group (block-uniform)

                // S^T = K Q^T : lane holds S^T[kv=mi*16+qd*4+r][q=l15]
                f32x4 s[4];
#pragma unroll
                for (int mi = 0; mi < 4; ++mi) s[mi] = zero4;
#pragma unroll
                for (int ks2 = 0; ks2 < 2; ++ks2)
#pragma unroll
                    for (int mi = 0; mi < 4; ++mi) {
                        const bf16x8 af =
                            *(const bf16x8*)&Ks[mi * 16 + l15][ks2 * 32 + qd * 8];
                        s[mi] = __builtin_amdgcn_mfma_f32_16x16x32_bf16(
                            af, qf[g][ks2], s[mi], 0, 0, 0);
                    }

                if (kt == diag) {   // causal mask: kv_loc > q_loc
#pragma unroll
                    for (int mi = 0; mi < 4; ++mi)
#pragma unroll
                        for (int r = 0; r < 4; ++r)
                            if (mi * 16 + qd * 4 + r > wid * 16 + l15)
                                s[mi][r] = -3.0e38f;
                }

                // per-lane softmax stats for this q-col (16 local + 2 shuffles)
                float mloc = -3.0e38f;
#pragma unroll
                for (int mi = 0; mi < 4; ++mi)
#pragma unroll
                    for (int r = 0; r < 4; ++r) mloc = fmaxf(mloc, s[mi][r]);
                mloc = fmaxf(mloc, __shfl_xor(mloc, 16));
                mloc = fmaxf(mloc, __shfl_xor(mloc, 32));
                const float mn = fmaxf(m_i[g], mloc);
                const float alpha = __expf(m_i[g] - mn);
                float rs = 0.f;
#pragma unroll
                for (int mi = 0; mi < 4; ++mi)
#pragma unroll
                    for (int r = 0; r < 4; ++r) {
                        const float e = __expf(s[mi][r] - mn);
                        s[mi][r] = e;
                        rs += e;
                    }
                rs += __shfl_xor(rs, 16);
                rs += __shfl_xor(rs, 32);
                l_i[g] = l_i[g] * alpha + rs;
                m_i[g] = mn;

                // P store (wave-private rows), packed 4x u16
#pragma unroll
                for (int mi = 0; mi < 4; ++mi) {
                    ushort4 w;
                    w.x = f2bf(s[mi][0]); w.y = f2bf(s[mi][1]);
                    w.z = f2bf(s[mi][2]); w.w = f2bf(s[mi][3]);
                    *(ushort4*)&Ps[g * 64 + wid * 16 + l15][mi * 16 + qd * 4] = w;
                }

                // rescale z rows by alpha of q-col qd*4+r
#pragma unroll
                for (int r = 0; r < 4; ++r) {
                    const float ar = __shfl(alpha, qd * 4 + r);
#pragma unroll
                    for (int ni = 0; ni < 4; ++ni) z[g][ni][r] *= ar;
                }

                // z += P V  (A = own P rows, same-wave DS ordering)
#pragma unroll
                for (int ks2 = 0; ks2 < 2; ++ks2) {
                    const bf16x8 ap =
                        *(const bf16x8*)&Ps[g * 64 + wid * 16 + l15][ks2 * 32 + qd * 8];
#pragma unroll
                    for (int ni = 0; ni < 4; ++ni) {
                        const bf16x8 bv =
                            *(const bf16x8*)&VsT[ni * 16 + l15][ks2 * 32 + qd * 8];
                        z[g][ni] = __builtin_amdgcn_mfma_f32_16x16x32_bf16(
                            ap, bv, z[g][ni], 0, 0, 0);
                    }
                }
            }
        }

        // z / l -> bf16, in-place over this q block
#pragma unroll
        for (int g = 0; g < 2; ++g) {
            const float linv = 1.0f / l_i[g];
#pragma unroll
            for (int r = 0; r < 4; ++r) {
                const float lr_ = __shfl(linv, qd * 4 + r);
                const size_t row = (size_t)qt * 128 + g * 64 + wid * 16 + qd * 4 + r;
#pragma unroll
                for (int ni = 0; ni < 4; ++ni)
                    qz[kbase + row * DM_ + ni * 16 + l15] = f2bf(z[g][ni][r] * lr_);
            }
        }
    }
}

extern "C" void kernel_launch(void* const* d_in, const int* in_sizes, int n_in,
                              void* d_out, int out_size, void* d_ws, size_t ws_size,
                              hipStream_t stream)
{
    const float* x_q  = (const float*)d_in[0];
    const float* x_kv = (const float*)d_in[1];
    // d_in[2] = mask (causal tril) -- computed analytically
    const float* W_Q  = (const float*)d_in[3];
    const float* W_K  = (const float*)d_in[4];
    const float* W_V  = (const float*)d_in[5];
    const float* W_O  = (const float*)d_in[6];
    const float* b_Q  = (const float*)d_in[7];
    const float* b_K  = (const float*)d_in[8];
    const float* b_V  = (const float*)d_in[9];
    const float* b_O  = (const float*)d_in[10];
    const float* ln1w = (const float*)d_in[11];
    const float* ln1b = (const float*)d_in[12];
    const float* ln2w = (const float*)d_in[13];
    const float* ln2b = (const float*)d_in[14];

    const size_t NTOK = (size_t)B_ * SQ_;          // 4096
    float* out  = (float*)d_out;
    float* kout = out + NTOK * DM_;
    float* vout = kout + NTOK * DM_;

    unsigned short* wsu  = (unsigned short*)d_ws;
    unsigned short* WTq  = wsu;                        // 1M elems
    unsigned short* WTkv = WTq + (1u << 20);           // 2M (K^T | V^T)
    unsigned short* WTo  = WTkv + (2u << 20);          // 1M
    unsigned short* qz   = WTo + (1u << 20);           // 4M
    unsigned short* kbf  = qz + (1u << 22);            // 4M
    unsigned short* vbfT = kbf + (1u << 22);           // 4M -> 32 MiB total

    transpose_all<<<1024, 256, 0, stream>>>(W_Q, W_K, W_V, W_O, WTq, WTkv, WTo);

    qkv_fused<<<768, 256, 0, stream>>>(x_q, x_kv, WTq, WTkv, b_Q, b_K, b_V,
                                       ln1w, ln1b, ln2w, ln2b,
                                       kout, vout, qz, kbf, vbfT);

    attn_mfma<<<dim3(8, NH_, B_), 256, 0, stream>>>(qz, kbf, vbfT);

    o_gemm<<<dim3(16, 32), 256, 0, stream>>>(qz, WTo, b_O, out);
}

// Round 7
// 246.656 us; speedup vs baseline: 1.1768x; 1.1768x over previous
//
#include <hip/hip_runtime.h>
#include <hip/hip_bf16.h>

#define B_   2
#define SQ_  2048
#define DM_  1024
#define NH_  16
#define DH_  64

typedef __attribute__((ext_vector_type(8))) short          bf16x8;
typedef __attribute__((ext_vector_type(8))) unsigned short u16x8;
typedef __attribute__((ext_vector_type(4))) float          f32x4;

__device__ __forceinline__ unsigned short f2bf(float f) {
    union { __hip_bfloat16 h; unsigned short u; } c;
    c.h = __float2bfloat16(f);   // RNE
    return c.u;
}
__device__ __forceinline__ float gsum16(float v) {
    v += __shfl_xor(v, 1);
    v += __shfl_xor(v, 2);
    v += __shfl_xor(v, 4);
    v += __shfl_xor(v, 8);
    return v;
}

// One launch: 4 weight transposes (bf16) + x_q/x_kv f32->bf16 conversion.
// bid<768: W_Q/W_K/W_V (16 mats of 1024x64 each, 256 blocks per tensor).
// 768..1023: W_O (1024x1024). 1024..1535: convert x_q (256) / x_kv (256).
__global__ __launch_bounds__(256) void prep_all(
    const float* __restrict__ W_Q, const float* __restrict__ W_K,
    const float* __restrict__ W_V, const float* __restrict__ W_O,
    const float* __restrict__ x_q, const float* __restrict__ x_kv,
    unsigned short* __restrict__ WTq, unsigned short* __restrict__ WTkv,
    unsigned short* __restrict__ WTo,
    unsigned short* __restrict__ xqbf, unsigned short* __restrict__ xkvbf)
{
    const int bid = blockIdx.x, tid = threadIdx.x;
    if (bid >= 1024) {   // elementwise f32 -> bf16 (16384-float chunks)
        const int cid = bid - 1024;
        const float* src = (cid < 256) ? x_q : x_kv;
        unsigned short* dst = (cid < 256) ? xqbf : xkvbf;
        const size_t base = (size_t)(cid & 255) * 16384 + tid * 4;
#pragma unroll
        for (int i = 0; i < 16; ++i) {
            const float4 v = *(const float4*)(src + base + i * 1024);
            ushort4 o;
            o.x = f2bf(v.x); o.y = f2bf(v.y); o.z = f2bf(v.z); o.w = f2bf(v.w);
            *(ushort4*)(dst + base + i * 1024) = o;
        }
        return;
    }
    __shared__ float t[64][65];
    const float* src; unsigned short* dst; int R, C, r0, c0;
    if (bid < 768) {
        const int which = bid >> 8, rem = bid & 255;
        const int rblk = rem & 15, zz = rem >> 4;
        src = (which == 0) ? W_Q : (which == 1) ? W_K : W_V;
        dst = (which == 0) ? WTq : (which == 1) ? WTkv : (WTkv + (1u << 20));
        src += (size_t)65536 * zz;
        dst += (size_t)65536 * zz;
        R = 1024; C = 64; r0 = rblk * 64; c0 = 0;
    } else {
        const int rem = bid - 768;
        src = W_O; dst = WTo; R = 1024; C = 1024;
        r0 = (rem & 15) * 64; c0 = (rem >> 4) * 64;
    }
    const int lr = tid >> 6, lc = tid & 63;
#pragma unroll
    for (int i = 0; i < 16; ++i)
        t[lr + i * 4][lc] = src[(size_t)(r0 + lr + i * 4) * C + c0 + lc];
    __syncthreads();
#pragma unroll
    for (int i = 0; i < 16; ++i)
        dst[(size_t)(c0 + lr + i * 4) * R + r0 + lc] = f2bf(t[lc][lr + i * 4]);
}

// C[4096 x N] = A[4096 x 1024] * W(+bias).  A bf16 [m][k]; WT bf16 [c][k].
// TM=128, BK=64, 256 threads. TN=128: waves 2x2. TN=64: waves 4x1.
// MODE 0: Q  -> per-head LN, bf16 out (Cb)
// MODE 1: KV -> N=2048; c<1024: K (LN, f32 Cf + bf16 Cb); c>=1024: V
//               (f32 Cf2 row-major + bf16 CbT transposed [b][h][d][s])
// MODE 2: O  -> f32 out (Cf)
template <int TN, int MODE>
__device__ __forceinline__ void gemm_body(
    unsigned short (*__restrict__ As)[72], unsigned short (*__restrict__ Bs)[72],
    int bx, int by, const unsigned short* __restrict__ Abf,
    const unsigned short* __restrict__ WT,
    const float* __restrict__ biasK, const float* __restrict__ biasV,
    const float* __restrict__ lnw, const float* __restrict__ lnb,
    float* __restrict__ Cf, float* __restrict__ Cf2,
    unsigned short* __restrict__ Cb, unsigned short* __restrict__ CbT, int tid)
{
    constexpr int MI = (TN == 128) ? 4 : 2;
    constexpr int BP = TN / 64;

    const int m0 = by * 128;
    const int c0 = bx * TN;

    const int srow = tid >> 2;
    const int skc  = (tid & 3) * 16;

    u16x8 ba[2][2];
    u16x8 bb[BP][2];

    const int wid = tid >> 6, lane = tid & 63;
    const int wm = (TN == 128) ? (wid >> 1) * 64 : wid * 32;
    const int wn = (TN == 128) ? (wid & 1) * 64 : 0;
    const int l15 = lane & 15, qd = lane >> 4;

    const f32x4 zero4 = {0.f, 0.f, 0.f, 0.f};
    f32x4 acc[MI][4];
#pragma unroll
    for (int mi = 0; mi < MI; ++mi)
#pragma unroll
        for (int ni = 0; ni < 4; ++ni) acc[mi][ni] = zero4;

#define LOAD_AB(kb)                                                             \
    {                                                                           \
        const size_t kof = (size_t)(kb) * 64 + skc;                             \
        for (int p = 0; p < 2; ++p) {                                           \
            const unsigned short* s =                                           \
                Abf + (size_t)(m0 + srow + p * 64) * 1024 + kof;                \
            ba[p][0] = *(const u16x8*)(s + 0);                                  \
            ba[p][1] = *(const u16x8*)(s + 8);                                  \
        }                                                                       \
        for (int p = 0; p < BP; ++p) {                                          \
            const unsigned short* s =                                           \
                WT + (size_t)(c0 + srow + p * 64) * 1024 + kof;                 \
            bb[p][0] = *(const u16x8*)(s + 0);                                  \
            bb[p][1] = *(const u16x8*)(s + 8);                                  \
        }                                                                       \
    }

    LOAD_AB(0)
    for (int kb = 0; kb < 16; ++kb) {
        __syncthreads();
#pragma unroll
        for (int p = 0; p < 2; ++p) {
            *(u16x8*)&As[srow + p * 64][skc + 0] = ba[p][0];
            *(u16x8*)&As[srow + p * 64][skc + 8] = ba[p][1];
        }
#pragma unroll
        for (int p = 0; p < BP; ++p) {
            *(u16x8*)&Bs[srow + p * 64][skc + 0] = bb[p][0];
            *(u16x8*)&Bs[srow + p * 64][skc + 8] = bb[p][1];
        }
        __syncthreads();
        if (kb < 15) LOAD_AB(kb + 1)
#pragma unroll
        for (int ks = 0; ks < 2; ++ks) {
            bf16x8 af[MI], bfr[4];
#pragma unroll
            for (int mi = 0; mi < MI; ++mi)
                af[mi] = *(const bf16x8*)&As[wm + mi * 16 + l15][ks * 32 + qd * 8];
#pragma unroll
            for (int ni = 0; ni < 4; ++ni)
                bfr[ni] = *(const bf16x8*)&Bs[wn + ni * 16 + l15][ks * 32 + qd * 8];
#pragma unroll
            for (int mi = 0; mi < MI; ++mi)
#pragma unroll
                for (int ni = 0; ni < 4; ++ni)
                    acc[mi][ni] = __builtin_amdgcn_mfma_f32_16x16x32_bf16(
                        af[mi], bfr[ni], acc[mi][ni], 0, 0, 0);
        }
    }
#undef LOAD_AB

    const float* bias = (MODE == 1 && c0 >= 1024) ? biasV : biasK;
    float bv[4];
#pragma unroll
    for (int ni = 0; ni < 4; ++ni) bv[ni] = bias[(c0 + wn + ni * 16 + l15) & 1023];
#pragma unroll
    for (int mi = 0; mi < MI; ++mi)
#pragma unroll
        for (int ni = 0; ni < 4; ++ni)
#pragma unroll
            for (int r = 0; r < 4; ++r) acc[mi][ni][r] += bv[ni];

    if constexpr (MODE != 2) {
        const bool doLN = (MODE == 0) || (c0 < 1024);
        if (doLN) {   // per-head LN: wave's 64 cols = exactly one head
            float w4[4], lb4[4];
#pragma unroll
            for (int ni = 0; ni < 4; ++ni) {
                w4[ni]  = lnw[ni * 16 + l15];
                lb4[ni] = lnb[ni * 16 + l15];
            }
#pragma unroll
            for (int mi = 0; mi < MI; ++mi)
#pragma unroll
                for (int r = 0; r < 4; ++r) {
                    float s1 = acc[mi][0][r] + acc[mi][1][r] + acc[mi][2][r] + acc[mi][3][r];
                    const float mu = gsum16(s1) * (1.0f / 64.0f);
                    float s2 = acc[mi][0][r] * acc[mi][0][r] + acc[mi][1][r] * acc[mi][1][r]
                             + acc[mi][2][r] * acc[mi][2][r] + acc[mi][3][r] * acc[mi][3][r];
                    const float var = gsum16(s2) * (1.0f / 64.0f) - mu * mu;
                    const float rstd = rsqrtf(var + 1e-5f);
#pragma unroll
                    for (int ni = 0; ni < 4; ++ni)
                        acc[mi][ni][r] = (acc[mi][ni][r] - mu) * rstd * w4[ni] + lb4[ni];
                }
        }
    }

    if constexpr (MODE == 0) {
#pragma unroll
        for (int mi = 0; mi < MI; ++mi)
#pragma unroll
            for (int r = 0; r < 4; ++r) {
                const size_t grow = m0 + wm + mi * 16 + qd * 4 + r;
#pragma unroll
                for (int ni = 0; ni < 4; ++ni)
                    Cb[grow * 1024 + c0 + wn + ni * 16 + l15] = f2bf(acc[mi][ni][r]);
            }
    } else if constexpr (MODE == 2) {
#pragma unroll
        for (int mi = 0; mi < MI; ++mi)
#pragma unroll
            for (int r = 0; r < 4; ++r) {
                const size_t grow = m0 + wm + mi * 16 + qd * 4 + r;
#pragma unroll
                for (int ni = 0; ni < 4; ++ni)
                    Cf[grow * 1024 + c0 + wn + ni * 16 + l15] = acc[mi][ni][r];
            }
    } else {
        if (c0 < 1024) {   // K half
#pragma unroll
            for (int mi = 0; mi < MI; ++mi)
#pragma unroll
                for (int r = 0; r < 4; ++r) {
                    const size_t grow = m0 + wm + mi * 16 + qd * 4 + r;
#pragma unroll
                    for (int ni = 0; ni < 4; ++ni) {
                        const int gcol = c0 + wn + ni * 16 + l15;
                        Cf[grow * 1024 + gcol] = acc[mi][ni][r];
                        Cb[grow * 1024 + gcol] = f2bf(acc[mi][ni][r]);
                    }
                }
        } else {           // V half: row-major f32 + transposed bf16
#pragma unroll
            for (int mi = 0; mi < MI; ++mi) {
                const int growb = m0 + wm + mi * 16 + qd * 4;
                const int bb_ = growb >> 11, ss = growb & 2047;
#pragma unroll
                for (int ni = 0; ni < 4; ++ni) {
                    const int gv = c0 - 1024 + wn + ni * 16 + l15;
                    const int hh = gv >> 6, dd = gv & 63;
#pragma unroll
                    for (int r = 0; r < 4; ++r)
                        Cf2[(size_t)(growb + r) * 1024 + gv] = acc[mi][ni][r];
                    ushort4 w;
                    w.x = f2bf(acc[mi][ni][0]); w.y = f2bf(acc[mi][ni][1]);
                    w.z = f2bf(acc[mi][ni][2]); w.w = f2bf(acc[mi][ni][3]);
                    *(ushort4*)&CbT[(((size_t)bb_ * NH_ + hh) * DH_ + dd) * SQ_ + ss] = w;
                }
            }
        }
    }
}

// Q gemm (256 blocks, TN=128) + KV gemm (512 blocks) in one 768-block launch.
__global__ __launch_bounds__(256) void qkv_fused(
    const unsigned short* __restrict__ xqbf, const unsigned short* __restrict__ xkvbf,
    const unsigned short* __restrict__ WTq, const unsigned short* __restrict__ WTkv,
    const float* __restrict__ b_Q, const float* __restrict__ b_K,
    const float* __restrict__ b_V,
    const float* __restrict__ ln1w, const float* __restrict__ ln1b,
    const float* __restrict__ ln2w, const float* __restrict__ ln2b,
    float* __restrict__ kout, float* __restrict__ vout,
    unsigned short* __restrict__ qz, unsigned short* __restrict__ kbf,
    unsigned short* __restrict__ vbfT)
{
    __shared__ __align__(16) unsigned short As[128][72];
    __shared__ __align__(16) unsigned short Bs[128][72];
    const int bid = blockIdx.x, tid = threadIdx.x;
    if (bid < 512) {
        gemm_body<128, 1>(As, Bs, bid & 15, bid >> 4, xkvbf, WTkv, b_K, b_V,
                          ln2w, ln2b, kout, vout, kbf, vbfT, tid);
    } else {
        const int b2 = bid - 512;
        gemm_body<128, 0>(As, Bs, b2 & 7, b2 >> 3, xqbf, WTq, b_Q, nullptr,
                          ln1w, ln1b, nullptr, nullptr, qz, nullptr, tid);
    }
}

__global__ __launch_bounds__(256) void o_gemm(
    const unsigned short* __restrict__ zbf, const unsigned short* __restrict__ WTo,
    const float* __restrict__ b_O, float* __restrict__ out)
{
    __shared__ __align__(16) unsigned short As[128][72];
    __shared__ __align__(16) unsigned short Bs[64][72];
    gemm_body<64, 2>(As, Bs, blockIdx.x, blockIdx.y, zbf, WTo, b_O, nullptr,
                     nullptr, nullptr, out, nullptr, nullptr, nullptr, threadIdx.x);
}

// causal flash attention, S^T formulation; 64 q-rows/block (4 waves x 16
// q-cols); paired hi-lo q-tiles (bx in 0..15 -> qt {31-bx, bx}: each tile
// exactly once, uniform 34 kv-tiles/block); K/V register prefetch.
__global__ __launch_bounds__(256) void attn_mfma(
    unsigned short* __restrict__ qz, const unsigned short* __restrict__ kbf,
    const unsigned short* __restrict__ vbfT)
{
    __shared__ __align__(16) unsigned short Ks[64][72];    // [kvrow][d]
    __shared__ __align__(16) unsigned short VsT[64][72];   // [d][kvrow]
    __shared__ __align__(16) unsigned short Ps[64][72];    // [qrow][kv] wave-private rows

    const int tid = threadIdx.x;
    const int h = blockIdx.y, b = blockIdx.z;
    const int wid = tid >> 6, lane = tid & 63;
    const int l15 = lane & 15, qd = lane >> 4;
    const int srow = tid >> 2, scol = (tid & 3) * 16;

    const size_t kbase = (size_t)b * SQ_ * DM_ + (size_t)h * DH_;
    const size_t vbase = ((size_t)b * NH_ + h) * DH_ * (size_t)SQ_;
    const f32x4 zero4 = {0.f, 0.f, 0.f, 0.f};

    for (int pass = 0; pass < 2; ++pass) {
        const int qt = pass ? blockIdx.x : 31 - blockIdx.x;   // bx 0..15

        // Q fragments (B-operand: n=l15 -> qrow, k=qd*8+j -> d), direct global
        bf16x8 qf[2];
        {
            const unsigned short* qp =
                qz + kbase + (size_t)(qt * 64 + wid * 16 + l15) * DM_ + qd * 8;
            qf[0] = *(const bf16x8*)(qp);
            qf[1] = *(const bf16x8*)(qp + 32);
        }

        f32x4 z[4];
#pragma unroll
        for (int ni = 0; ni < 4; ++ni) z[ni] = zero4;
        float m_i = -3.0e38f, l_i = 0.f;

        u16x8 kr0, kr1, vr0, vr1;
        {
            const unsigned short* ks = kbf + kbase + (size_t)srow * DM_ + scol;
            kr0 = *(const u16x8*)(ks);
            kr1 = *(const u16x8*)(ks + 8);
            const unsigned short* vs = vbfT + vbase + (size_t)srow * SQ_ + scol;
            vr0 = *(const u16x8*)(vs);
            vr1 = *(const u16x8*)(vs + 8);
        }

        for (int kt = 0; kt <= qt; ++kt) {
            __syncthreads();   // prior tile's reads of Ks/VsT complete
            *(u16x8*)&Ks[srow][scol + 0]  = kr0;
            *(u16x8*)&Ks[srow][scol + 8]  = kr1;
            *(u16x8*)&VsT[srow][scol + 0] = vr0;
            *(u16x8*)&VsT[srow][scol + 8] = vr1;
            __syncthreads();
            if (kt < qt) {   // prefetch next tile (overlaps compute)
                const unsigned short* ks =
                    kbf + kbase + (size_t)((kt + 1) * 64 + srow) * DM_ + scol;
                kr0 = *(const u16x8*)(ks);
                kr1 = *(const u16x8*)(ks + 8);
                const unsigned short* vs =
                    vbfT + vbase + (size_t)srow * SQ_ + (kt + 1) * 64 + scol;
                vr0 = *(const u16x8*)(vs);
                vr1 = *(const u16x8*)(vs + 8);
            }

            // S^T = K Q^T : lane holds S^T[kv=mi*16+qd*4+r][q=l15]
            f32x4 s[4];
#pragma unroll
            for (int mi = 0; mi < 4; ++mi) s[mi] = zero4;
#pragma unroll
            for (int ks2 = 0; ks2 < 2; ++ks2)
#pragma unroll
                for (int mi = 0; mi < 4; ++mi) {
                    const bf16x8 af = *(const bf16x8*)&Ks[mi * 16 + l15][ks2 * 32 + qd * 8];
                    s[mi] = __builtin_amdgcn_mfma_f32_16x16x32_bf16(af, qf[ks2], s[mi], 0, 0, 0);
                }

            if (kt == qt) {   // causal mask (tile-local): kv > q
#pragma unroll
                for (int mi = 0; mi < 4; ++mi)
#pragma unroll
                    for (int r = 0; r < 4; ++r)
                        if (mi * 16 + qd * 4 + r > wid * 16 + l15) s[mi][r] = -3.0e38f;
            }

            // per-lane softmax stats for qcol=l15 (16 local + 2 shuffles)
            float mloc = -3.0e38f;
#pragma unroll
            for (int mi = 0; mi < 4; ++mi)
#pragma unroll
                for (int r = 0; r < 4; ++r) mloc = fmaxf(mloc, s[mi][r]);
            mloc = fmaxf(mloc, __shfl_xor(mloc, 16));
            mloc = fmaxf(mloc, __shfl_xor(mloc, 32));
            const float mn = fmaxf(m_i, mloc);
            const float alpha = __expf(m_i - mn);
            float rs = 0.f;
#pragma unroll
            for (int mi = 0; mi < 4; ++mi)
#pragma unroll
                for (int r = 0; r < 4; ++r) {
                    const float e = __expf(s[mi][r] - mn);
                    s[mi][r] = e;
                    rs += e;
                }
            rs += __shfl_xor(rs, 16);
            rs += __shfl_xor(rs, 32);
            l_i = l_i * alpha + rs;
            m_i = mn;

            // P store (wave-private rows), packed 4x u16
#pragma unroll
            for (int mi = 0; mi < 4; ++mi) {
                ushort4 w;
                w.x = f2bf(s[mi][0]); w.y = f2bf(s[mi][1]);
                w.z = f2bf(s[mi][2]); w.w = f2bf(s[mi][3]);
                *(ushort4*)&Ps[wid * 16 + l15][mi * 16 + qd * 4] = w;
            }

            // rescale z rows by alpha of qcol qd*4+r
#pragma unroll
            for (int r = 0; r < 4; ++r) {
                const float ar = __shfl(alpha, qd * 4 + r);
#pragma unroll
                for (int ni = 0; ni < 4; ++ni) z[ni][r] *= ar;
            }

            // z += P V (A = own P rows, same-wave DS ordering)
#pragma unroll
            for (int ks2 = 0; ks2 < 2; ++ks2) {
                const bf16x8 ap = *(const bf16x8*)&Ps[wid * 16 + l15][ks2 * 32 + qd * 8];
#pragma unroll
                for (int ni = 0; ni < 4; ++ni) {
                    const bf16x8 bv = *(const bf16x8*)&VsT[ni * 16 + l15][ks2 * 32 + qd * 8];
                    z[ni] = __builtin_amdgcn_mfma_f32_16x16x32_bf16(ap, bv, z[ni], 0, 0, 0);
                }
            }
        }

        const float linv = 1.0f / l_i;
#pragma unroll
        for (int r = 0; r < 4; ++r) {
            const float lr_ = __shfl(linv, qd * 4 + r);
            const size_t row = (size_t)qt * 64 + wid * 16 + qd * 4 + r;
#pragma unroll
            for (int ni = 0; ni < 4; ++ni)
                qz[kbase + row * DM_ + ni * 16 + l15] = f2bf(z[ni][r] * lr_);
        }
    }
}

extern "C" void kernel_launch(void* const* d_in, const int* in_sizes, int n_in,
                              void* d_out, int out_size, void* d_ws, size_t ws_size,
                              hipStream_t stream)
{
    const float* x_q  = (const float*)d_in[0];
    const float* x_kv = (const float*)d_in[1];
    // d_in[2] = mask (causal tril) -- computed analytically
    const float* W_Q  = (const float*)d_in[3];
    const float* W_K  = (const float*)d_in[4];
    const float* W_V  = (const float*)d_in[5];
    const float* W_O  = (const float*)d_in[6];
    const float* b_Q  = (const float*)d_in[7];
    const float* b_K  = (const float*)d_in[8];
    const float* b_V  = (const float*)d_in[9];
    const float* b_O  = (const float*)d_in[10];
    const float* ln1w = (const float*)d_in[11];
    const float* ln1b = (const float*)d_in[12];
    const float* ln2w = (const float*)d_in[13];
    const float* ln2b = (const float*)d_in[14];

    const size_t NTOK = (size_t)B_ * SQ_;          // 4096
    float* out  = (float*)d_out;
    float* kout = out + NTOK * DM_;
    float* vout = kout + NTOK * DM_;

    // bf16 copies of x_q/x_kv live in the `out` region (16 MB) of d_out:
    // written by prep_all, read by qkv_fused, overwritten by o_gemm last.
    unsigned short* xqbf  = (unsigned short*)out;
    unsigned short* xkvbf = xqbf + (1u << 22);

    unsigned short* wsu  = (unsigned short*)d_ws;
    unsigned short* WTq  = wsu;                        // 1M elems
    unsigned short* WTkv = WTq + (1u << 20);           // 2M (K^T | V^T)
    unsigned short* WTo  = WTkv + (2u << 20);          // 1M
    unsigned short* qz   = WTo + (1u << 20);           // 4M
    unsigned short* kbf  = qz + (1u << 22);            // 4M
    unsigned short* vbfT = kbf + (1u << 22);           // 4M -> 32 MiB total

    prep_all<<<1536, 256, 0, stream>>>(W_Q, W_K, W_V, W_O, x_q, x_kv,
                                       WTq, WTkv, WTo, xqbf, xkvbf);

    qkv_fused<<<768, 256, 0, stream>>>(xqbf, xkvbf, WTq, WTkv, b_Q, b_K, b_V,
                                       ln1w, ln1b, ln2w, ln2b,
                                       kout, vout, qz, kbf, vbfT);

    attn_mfma<<<dim3(16, NH_, B_), 256, 0, stream>>>(qz, kbf, vbfT);

    o_gemm<<<dim3(16, 32), 256, 0, stream>>>(qz, WTo, b_O, out);
}